// Round 6
// baseline (249.285 us; speedup 1.0000x reference)
//
#include <hip/hip_runtime.h>

typedef __bf16 bf16x8 __attribute__((ext_vector_type(8)));
typedef float  f32x4  __attribute__((ext_vector_type(4)));

// ---- LDS layout (bytes), 1024-thread block, 32 pixels ----
// x : [96][256] bf16 swz off=(m*512+2c)^((m&7)<<4)           [0,49152)
//     later y: [32][768] bf16 swz off=(p*1536+2k)^((p&7)<<4)  aliases x (y written after all x reads)
// o : [96][256] bf16 swz off=(m*512+2d)^((m&7)<<4)           [49152,98304)
// ps: [96][16] f32                                            [98304,104448)
// pq: [96][16] f32                                            [104448,110592)
// mu: [96] f32  rs: [96] f32                                  [110592,111360)
#define XOFF 0
#define OOFF 49152
#define PSOFF 98304
#define PQOFF 104448
#define MUOFF 110592
#define RSOFF 110976
#define SMEM_BYTES 111360

static __device__ __forceinline__ unsigned short f2b(float f) {
  __bf16 h = (__bf16)f;
  return __builtin_bit_cast(unsigned short, h);
}

__global__ void convert_weights(const float* __restrict__ w_in,
                                const float* __restrict__ w_out,
                                const float* __restrict__ w_conv,
                                __bf16* __restrict__ ws) {
  int gid = blockIdx.x * 256 + threadIdx.x;   // 0..114687
  int i4 = gid * 4;
  const float* src;
  int off;
  if (i4 < 196608)      { src = w_in;   off = i4; }
  else if (i4 < 262144) { src = w_out;  off = i4 - 196608; }
  else                  { src = w_conv; off = i4 - 262144; }
  float4 f = *(const float4*)(src + off);
  ws[i4 + 0] = (__bf16)f.x;
  ws[i4 + 1] = (__bf16)f.y;
  ws[i4 + 2] = (__bf16)f.z;
  ws[i4 + 3] = (__bf16)f.w;
}

__global__ __launch_bounds__(1024) void crf_fused(
    const float* __restrict__ cort,
    const float* __restrict__ subc,
    const float* __restrict__ vent,
    const __bf16* __restrict__ w_in,
    const float* __restrict__ b_in,
    const __bf16* __restrict__ w_out,
    const float* __restrict__ b_out,
    const float* __restrict__ gamma,
    const float* __restrict__ beta,
    const __bf16* __restrict__ w_conv,
    const float* __restrict__ b_conv,
    float* __restrict__ out) {
  extern __shared__ char smem[];
  const int tid  = threadIdx.x;
  const int lane = tid & 63;
  const int wv   = tid >> 6;          // 0..15
  const int l15  = lane & 15;
  const int l4   = lane >> 4;
  const int blk  = blockIdx.x;
  const int img  = blk >> 7;                 // 128 blocks per image
  const int pixbase = (blk & 127) << 5;      // 32 pixels per block
  const size_t base = (size_t)img * (256 * 4096) + pixbase;

  // ---------- stage x -> LDS bf16 [96][256] swz; 2x float4 reads, 4 dword LDS writes ----------
  {
    const int p4 = (tid & 7) * 4;     // pixel quad
    const int c  = (tid >> 3) * 2;    // channel pair
#pragma unroll
    for (int si = 0; si < 3; ++si) {
      const float* rp = (si == 0) ? cort : (si == 1) ? subc : vent;
      rp += base;
      float4 fa = *(const float4*)(rp + (size_t)c * 4096 + p4);
      float4 fb = *(const float4*)(rp + (size_t)(c + 1) * 4096 + p4);
#pragma unroll
      for (int k = 0; k < 4; ++k) {
        int m = si * 32 + p4 + k;
        float va = (k == 0) ? fa.x : (k == 1) ? fa.y : (k == 2) ? fa.z : fa.w;
        float vb = (k == 0) ? fb.x : (k == 1) ? fb.y : (k == 2) ? fb.z : fb.w;
        unsigned off = ((unsigned)(m * 512 + c * 2)) ^ ((unsigned)(m & 7) << 4);
        *(unsigned*)(smem + XOFF + off) = (unsigned)f2b(va) | ((unsigned)f2b(vb) << 16);
      }
    }
  }
  __syncthreads();   // B1

  // ---------- QKV + in-register attention: wave = (head h, pixel-half ph), one shot ----------
  {
    const int h  = wv >> 1;
    const int ph = wv & 1;
    const float SC = 0.17677669529663687f;  // 1/sqrt(32)
    f32x4 acc[3][6] = {};   // [token s][0,1=q 2,3=k 4,5=v]
#pragma unroll
    for (int ks = 0; ks < 8; ++ks) {
      const int k0 = ks * 32;
      bf16x8 af[3];
#pragma unroll
      for (int s = 0; s < 3; ++s) {
        int m = s * 32 + ph * 16 + l15;
        unsigned off = ((unsigned)(m * 512 + (k0 + l4 * 8) * 2)) ^ ((unsigned)(m & 7) << 4);
        af[s] = *(const bf16x8*)(smem + XOFF + off);
      }
#pragma unroll
      for (int j = 0; j < 6; ++j) {
        int jb = (j >> 1) * 256 + h * 32 + (j & 1) * 16 + l15;
        bf16x8 bfr = *(const bf16x8*)(w_in + (size_t)jb * 256 + k0 + l4 * 8);
#pragma unroll
        for (int s = 0; s < 3; ++s)
          acc[s][j] = __builtin_amdgcn_mfma_f32_16x16x32_bf16(af[s], bfr, acc[s][j], 0, 0, 0);
      }
    }
    // bias add (zeros here, kept for generality)
#pragma unroll
    for (int jq = 0; jq < 2; ++jq) {
      float bq = b_in[h * 32 + jq * 16 + l15];
      float bk = b_in[256 + h * 32 + jq * 16 + l15];
      float bv = b_in[512 + h * 32 + jq * 16 + l15];
#pragma unroll
      for (int s = 0; s < 3; ++s)
#pragma unroll
        for (int r = 0; r < 4; ++r) {
          acc[s][jq][r]     += bq;
          acc[s][2 + jq][r] += bk;
          acc[s][4 + jq][r] += bv;
        }
    }
    // attention: lane holds d=jq*16+l15 of pixel p=ph*16+l4*4+r
#pragma unroll
    for (int si = 0; si < 3; ++si) {
      float pp[3][4];
#pragma unroll
      for (int ti = 0; ti < 3; ++ti)
#pragma unroll
        for (int r = 0; r < 4; ++r)
          pp[ti][r] = acc[si][0][r] * acc[ti][2][r] + acc[si][1][r] * acc[ti][3][r];
#pragma unroll
      for (int mask = 1; mask <= 8; mask <<= 1)
#pragma unroll
        for (int ti = 0; ti < 3; ++ti)
#pragma unroll
          for (int r = 0; r < 4; ++r)
            pp[ti][r] += __shfl_xor(pp[ti][r], mask);
#pragma unroll
      for (int r = 0; r < 4; ++r) {
        float s0 = pp[0][r] * SC, s1 = pp[1][r] * SC, s2 = pp[2][r] * SC;
        float mx = fmaxf(fmaxf(s0, s1), s2);
        float e0 = __expf(s0 - mx), e1 = __expf(s1 - mx), e2 = __expf(s2 - mx);
        float inv = 1.f / (e0 + e1 + e2);
        e0 *= inv; e1 *= inv; e2 *= inv;
        int m = si * 32 + ph * 16 + l4 * 4 + r;
#pragma unroll
        for (int jq = 0; jq < 2; ++jq) {
          float ov = e0 * acc[0][4 + jq][r] + e1 * acc[1][4 + jq][r] + e2 * acc[2][4 + jq][r];
          int d = h * 32 + jq * 16 + l15;
          unsigned off = ((unsigned)(m * 512 + d * 2)) ^ ((unsigned)(m & 7) << 4);
          *(__bf16*)(smem + OOFF + off) = (__bf16)ov;
        }
      }
    }
  }
  __syncthreads();   // B2: o[96][256] complete

  // ---------- out_proj GEMM: wave owns 16 N-cols; accY[6] only live accumulator ----------
  f32x4 accY[6] = {};
#pragma unroll
  for (int ks = 0; ks < 8; ++ks) {
    const int k0 = ks * 32;
    bf16x8 bfr = *(const bf16x8*)(w_out + (size_t)(wv * 16 + l15) * 256 + k0 + l4 * 8);
#pragma unroll
    for (int i = 0; i < 6; ++i) {
      int m = i * 16 + l15;
      unsigned off = ((unsigned)(m * 512 + (k0 + l4 * 8) * 2)) ^ ((unsigned)(m & 7) << 4);
      bf16x8 af = *(const bf16x8*)(smem + OOFF + off);
      accY[i] = __builtin_amdgcn_mfma_f32_16x16x32_bf16(af, bfr, accY[i], 0, 0, 0);
    }
  }

  // ---------- bias + residual + LayerNorm partials (wave owns 16 cols) ----------
  {
    const int jc = wv * 16 + l15;
    float bo = b_out[jc];
#pragma unroll
    for (int i = 0; i < 6; ++i)
#pragma unroll
      for (int r = 0; r < 4; ++r) {
        int m = i * 16 + l4 * 4 + r;
        unsigned xo = ((unsigned)(m * 512 + jc * 2)) ^ ((unsigned)(m & 7) << 4);
        float xv = (float)(*(const __bf16*)(smem + XOFF + xo));
        float v = accY[i][r] + bo + xv;
        accY[i][r] = v;
        float s1 = v, s2 = v * v;
        s1 += __shfl_xor(s1, 1); s2 += __shfl_xor(s2, 1);
        s1 += __shfl_xor(s1, 2); s2 += __shfl_xor(s2, 2);
        s1 += __shfl_xor(s1, 4); s2 += __shfl_xor(s2, 4);
        s1 += __shfl_xor(s1, 8); s2 += __shfl_xor(s2, 8);
        if (l15 == 0) {
          *(float*)(smem + PSOFF + (m * 16 + wv) * 4) = s1;
          *(float*)(smem + PQOFF + (m * 16 + wv) * 4) = s2;
        }
      }
  }
  __syncthreads();   // B3
  if (tid < 96) {
    float s = 0.f, q = 0.f;
#pragma unroll
    for (int j = 0; j < 16; ++j) {
      s += *(const float*)(smem + PSOFF + (tid * 16 + j) * 4);
      q += *(const float*)(smem + PQOFF + (tid * 16 + j) * 4);
    }
    float mu  = s * (1.f / 256.f);
    float var = q * (1.f / 256.f) - mu * mu;
    *(float*)(smem + MUOFF + tid * 4) = mu;
    *(float*)(smem + RSOFF + tid * 4) = rsqrtf(var + 1e-5f);
  }
  __syncthreads();   // B4
  // rescale + write y bf16 into [32][768] swz (aliases x; all x reads complete)
  {
    const int jc = wv * 16 + l15;
    float gg = gamma[jc];
    float bb = beta[jc];
#pragma unroll
    for (int i = 0; i < 6; ++i)
#pragma unroll
      for (int r = 0; r < 4; ++r) {
        int m = i * 16 + l4 * 4 + r;
        float mu = *(const float*)(smem + MUOFF + m * 4);
        float rs = *(const float*)(smem + RSOFF + m * 4);
        float yv = (accY[i][r] - mu) * rs * gg + bb;
        int p = m & 31, s = m >> 5;
        int kk = s * 256 + jc;
        unsigned off = ((unsigned)(p * 1536 + kk * 2)) ^ ((unsigned)(p & 7) << 4);
        *(__bf16*)(smem + XOFF + off) = (__bf16)yv;
      }
  }
  __syncthreads();   // B5

  // ---------- 1x1 conv: wave owns 16 cout; N=32 pixels; K=768 ----------
  {
    f32x4 accC[2] = {};
#pragma unroll 4
    for (int ks = 0; ks < 24; ++ks) {
      const int k0 = ks * 32;
      bf16x8 af = *(const bf16x8*)(w_conv + (size_t)(wv * 16 + l15) * 768 + k0 + l4 * 8);
#pragma unroll
      for (int j = 0; j < 2; ++j) {
        int p = j * 16 + l15;
        unsigned off = ((unsigned)(p * 1536 + (k0 + l4 * 8) * 2)) ^ ((unsigned)(p & 7) << 4);
        bf16x8 bfr = *(const bf16x8*)(smem + XOFF + off);
        accC[j] = __builtin_amdgcn_mfma_f32_16x16x32_bf16(af, bfr, accC[j], 0, 0, 0);
      }
    }
#pragma unroll
    for (int r = 0; r < 4; ++r) {
      int co = wv * 16 + l4 * 4 + r;
      float cb = b_conv[co];
#pragma unroll
      for (int j = 0; j < 2; ++j)
        out[((size_t)img * 256 + co) * 4096 + pixbase + j * 16 + l15] = accC[j][r] + cb;
    }
  }
}

extern "C" void kernel_launch(void* const* d_in, const int* in_sizes, int n_in,
                              void* d_out, int out_size, void* d_ws, size_t ws_size,
                              hipStream_t stream) {
  (void)in_sizes; (void)n_in; (void)out_size; (void)ws_size;
  const float* cort    = (const float*)d_in[0];
  const float* subc    = (const float*)d_in[1];
  const float* vent    = (const float*)d_in[2];
  const float* w_in_f  = (const float*)d_in[3];
  const float* b_in    = (const float*)d_in[4];
  const float* w_out_f = (const float*)d_in[5];
  const float* b_out   = (const float*)d_in[6];
  const float* gamma   = (const float*)d_in[7];
  const float* beta    = (const float*)d_in[8];
  const float* w_conv_f= (const float*)d_in[9];
  const float* b_conv  = (const float*)d_in[10];

  __bf16* ws = (__bf16*)d_ws;   // 458752 bf16 = 917504 B
  convert_weights<<<448, 256, 0, stream>>>(w_in_f, w_out_f, w_conv_f, ws);
  crf_fused<<<1024, 1024, SMEM_BYTES, stream>>>(
      cort, subc, vent,
      ws,            b_in,
      ws + 196608,   b_out,
      gamma,         beta,
      ws + 262144,   b_conv,
      (float*)d_out);
}